// Round 9
// baseline (73.523 us; speedup 1.0000x reference)
//
#include <hip/hip_runtime.h>
#include <hip/hip_fp16.h>

#define BATCH 32
#define TLEN  4096
#define CH    128      // C == F == 128
#define KW    3
#define DIL   8

#define BM    64                 // output rows per tile
#define HROWS (BM + 2 * DIL)     // 80  h rows
#define XROWS (BM + 4 * DIL)     // 96  x rows
#define LDSC  136                // 272B row stride: 16B-aligned, 2-way bank alias (free)
#define TPB   4                  // tiles per (persistent) block

typedef _Float16 f16x8 __attribute__((ext_vector_type(8)));
typedef float    f32x4 __attribute__((ext_vector_type(4)));

// ---------------------------------------------------------------------------
// Prep: Wt[j][f][c] = (f16) W[c][j][f]   for both layers' kernels.
// ---------------------------------------------------------------------------
__global__ void prep_weights_kernel(const float* __restrict__ W1,
                                    const float* __restrict__ W2,
                                    _Float16* __restrict__ Wt1,
                                    _Float16* __restrict__ Wt2) {
    const int total = KW * CH * CH;
    int idx = blockIdx.x * 256 + threadIdx.x;
    if (idx >= 2 * total) return;
    const float* W  = (idx < total) ? W1 : W2;
    _Float16*    Wt = (idx < total) ? Wt1 : Wt2;
    int r = idx % total;
    int j = r / (CH * CH);
    int f = (r / CH) % CH;
    int c = r % CH;
    Wt[j * CH * CH + f * CH + c] = (_Float16)W[c * (KW * CH) + j * CH + f];
}

// ---------------------------------------------------------------------------
// Fused TemporalDeConvBlock — persistent blocks, 4 tiles each, software-
// pipelined x staging: next tile's global loads are issued after G1 (x-buf
// dead) and land in registers across {h-store, barrier, G2}; convert+write
// to LDS after G2. Plain reg-loads survive __syncthreads (no vmcnt drain —
// that applies to global_load_lds only), so HBM latency hides under MFMA.
// 256 thr = 4 waves; wave w owns cols [32w,32w+32) as two 16-col subtiles
// (each A ds_read feeds 2 MFMA). Weights reload per tile from L2; only one
// layer's 96-VGPR slice is live at a time.
// Register audit: peak ~200 (h-store: acc1 40 + w2 96 + sv 48 + temps).
// LESSONS: caps below live-set spill catastrophically (r3/r5); 512-thread
// blocks get pinned to 64 VGPR (r4/r6/r7) -> 256 threads, no wave bound.
// ---------------------------------------------------------------------------
__global__ __launch_bounds__(256)
void fused_deconv_kernel(const float* __restrict__ x,
                         const _Float16* __restrict__ Wt1,
                         const float* __restrict__ bias1,
                         const _Float16* __restrict__ Wt2,
                         const float* __restrict__ bias2,
                         float* __restrict__ out)
{
    __shared__ __align__(16) _Float16 xs[XROWS][LDSC];   // 96*272  = 26112 B
    __shared__ __align__(16) _Float16 hs[HROWS][LDSC];   // 80*272  = 21760 B

    const int tid  = threadIdx.x;
    const int lane = tid & 63;
    const int wid  = tid >> 6;         // 0..3
    const int l15  = lane & 15;
    const int kg   = lane >> 4;        // 0..3
    const int nc   = wid << 5;         // wave column base: 0,32,64,96

    const int bt    = blockIdx.x;
    const int b     = bt >> 4;                 // 16 blocks per batch
    const int tbase = (bt & 15) << 8;          // 4 tiles * 64 rows

    const float bv1_0 = 128.0f * bias1[nc + l15];
    const float bv1_1 = 128.0f * bias1[nc + 16 + l15];
    const float bv2_0 = 128.0f * bias2[nc + l15];
    const float bv2_1 = 128.0f * bias2[nc + 16 + l15];

    // ---- prologue: load w1 (in flight over stage) + stage tile 0 directly
    f16x8 w1[12][2];
#pragma unroll
    for (int ks = 0; ks < 12; ++ks) {
        const int j  = ks >> 2;
        const int c0 = (ks & 3) << 5;
        const _Float16* wb = Wt1 + (size_t)j * (CH * CH) + c0 + kg * 8;
        w1[ks][0] = *(const f16x8*)(wb + (nc + l15) * CH);
        w1[ks][1] = *(const f16x8*)(wb + (nc + 16 + l15) * CH);
    }
#pragma unroll
    for (int p = 0; p < 6; ++p) {
        const int i   = tid + 256 * p;
        const int row = i >> 4;
        const int c8  = (i & 15) << 3;
        const int t   = tbase + row;
        f16x8 o;
        if (t < TLEN) {
            const float* xp = x + ((size_t)b * TLEN + t) * CH + c8;
            f32x4 v0 = *(const f32x4*)(xp + 0);
            f32x4 v1 = *(const f32x4*)(xp + 4);
            o[0] = (_Float16)v0[0]; o[1] = (_Float16)v0[1];
            o[2] = (_Float16)v0[2]; o[3] = (_Float16)v0[3];
            o[4] = (_Float16)v1[0]; o[5] = (_Float16)v1[1];
            o[6] = (_Float16)v1[2]; o[7] = (_Float16)v1[3];
        } else {
            o = (f16x8){};
        }
        *(f16x8*)&xs[row][c8] = o;
    }
    __syncthreads();

    f32x4 sv[6][2];   // in-flight next-tile stage registers (48 VGPR)

    for (int q = 0; q < TPB; ++q) {
        const int t0 = tbase + (q << 6);

        // ---- GEMM1: h rows 0..79, cols [nc,nc+32) — 120 MFMA / 60 ds_read
        f32x4 acc1[5][2];
#pragma unroll
        for (int m = 0; m < 5; ++m) {
            acc1[m][0] = (f32x4){0.f, 0.f, 0.f, 0.f};
            acc1[m][1] = (f32x4){0.f, 0.f, 0.f, 0.f};
        }
#pragma unroll
        for (int ks = 0; ks < 12; ++ks) {
            const int j     = ks >> 2;
            const int c0    = (ks & 3) << 5;
            const int shift = (2 - j) * DIL;
#pragma unroll
            for (int m = 0; m < 5; ++m) {
                f16x8 af = *(const f16x8*)&xs[m * 16 + shift + l15][c0 + kg * 8];
                acc1[m][0] = __builtin_amdgcn_mfma_f32_16x16x32_f16(af, w1[ks][0], acc1[m][0], 0, 0, 0);
                acc1[m][1] = __builtin_amdgcn_mfma_f32_16x16x32_f16(af, w1[ks][1], acc1[m][1], 0, 0, 0);
            }
        }

        // ---- load w2 (in flight across h-store + barrier; w1 slice dead)
        f16x8 w2[12][2];
#pragma unroll
        for (int ks = 0; ks < 12; ++ks) {
            const int j  = ks >> 2;
            const int c0 = (ks & 3) << 5;
            const _Float16* wb = Wt2 + (size_t)j * (CH * CH) + c0 + kg * 8;
            w2[ks][0] = *(const f16x8*)(wb + (nc + l15) * CH);
            w2[ks][1] = *(const f16x8*)(wb + (nc + 16 + l15) * CH);
        }

        // ---- issue next tile's x loads (x-buf dead after G1; these fly
        // across h-store + barrier + G2, landing in sv registers)
        if (q < TPB - 1) {
            const int tn = t0 + BM;
#pragma unroll
            for (int p = 0; p < 6; ++p) {
                const int i   = tid + 256 * p;
                const int row = i >> 4;
                const int c8  = (i & 15) << 3;
                const int t   = tn + row;
                if (t < TLEN) {
                    const float* xp = x + ((size_t)b * TLEN + t) * CH + c8;
                    sv[p][0] = *(const f32x4*)(xp + 0);
                    sv[p][1] = *(const f32x4*)(xp + 4);
                } else {
                    sv[p][0] = (f32x4){0.f, 0.f, 0.f, 0.f};
                    sv[p][1] = (f32x4){0.f, 0.f, 0.f, 0.f};
                }
            }
        }

        // ---- h-store: acc1 -> hs (relu + bias; rows past TLEN zero)
#pragma unroll
        for (int m = 0; m < 5; ++m) {
#pragma unroll
            for (int nn = 0; nn < 2; ++nn) {
                const float bv = nn ? bv1_1 : bv1_0;
                const int f = nc + nn * 16 + l15;
#pragma unroll
                for (int i = 0; i < 4; ++i) {
                    const int r = m * 16 + kg * 4 + i;
                    const int u = t0 + r;
                    const int nv = 1 + (u < TLEN - DIL) + (u < TLEN - 2 * DIL);
                    float v = acc1[m][nn][i] + (float)nv * bv;
                    v = fmaxf(v, 0.0f);
                    hs[r][f] = (u < TLEN) ? (_Float16)v : (_Float16)0.0f;
                }
            }
        }
        __syncthreads();   // hs visible; all waves past G1 (xs dead)

        // ---- GEMM2: out rows 0..63, cols [nc,nc+32) — 96 MFMA / 48 ds_read
        f32x4 acc2[4][2];
#pragma unroll
        for (int m = 0; m < 4; ++m) {
            acc2[m][0] = (f32x4){0.f, 0.f, 0.f, 0.f};
            acc2[m][1] = (f32x4){0.f, 0.f, 0.f, 0.f};
        }
#pragma unroll
        for (int ks = 0; ks < 12; ++ks) {
            const int j     = ks >> 2;
            const int c0    = (ks & 3) << 5;
            const int shift = (2 - j) * DIL;
#pragma unroll
            for (int m = 0; m < 4; ++m) {
                f16x8 af = *(const f16x8*)&hs[m * 16 + shift + l15][c0 + kg * 8];
                acc2[m][0] = __builtin_amdgcn_mfma_f32_16x16x32_f16(af, w2[ks][0], acc2[m][0], 0, 0, 0);
                acc2[m][1] = __builtin_amdgcn_mfma_f32_16x16x32_f16(af, w2[ks][1], acc2[m][1], 0, 0, 0);
            }
        }

        // ---- convert + write the staged next-tile window into xs
        if (q < TPB - 1) {
#pragma unroll
            for (int p = 0; p < 6; ++p) {
                const int i   = tid + 256 * p;
                const int row = i >> 4;
                const int c8  = (i & 15) << 3;
                f16x8 o;
                o[0] = (_Float16)sv[p][0][0]; o[1] = (_Float16)sv[p][0][1];
                o[2] = (_Float16)sv[p][0][2]; o[3] = (_Float16)sv[p][0][3];
                o[4] = (_Float16)sv[p][1][0]; o[5] = (_Float16)sv[p][1][1];
                o[6] = (_Float16)sv[p][1][2]; o[7] = (_Float16)sv[p][1][3];
                *(f16x8*)&xs[row][c8] = o;
            }
            // ---- reload w1 for next tile (in flight across epilogue+barrier)
#pragma unroll
            for (int ks = 0; ks < 12; ++ks) {
                const int j  = ks >> 2;
                const int c0 = (ks & 3) << 5;
                const _Float16* wb = Wt1 + (size_t)j * (CH * CH) + c0 + kg * 8;
                w1[ks][0] = *(const f16x8*)(wb + (nc + l15) * CH);
                w1[ks][1] = *(const f16x8*)(wb + (nc + 16 + l15) * CH);
            }
        }

        // ---- epilogue: residual prefetch, then bias2+relu+residual+relu+store
        float rx[4][2][4];
#pragma unroll
        for (int m = 0; m < 4; ++m)
#pragma unroll
            for (int nn = 0; nn < 2; ++nn) {
                const int f = nc + nn * 16 + l15;
#pragma unroll
                for (int i = 0; i < 4; ++i) {
                    const int r = m * 16 + kg * 4 + i;
                    rx[m][nn][i] = x[((size_t)b * TLEN + t0 + r) * CH + f];
                }
            }
#pragma unroll
        for (int m = 0; m < 4; ++m) {
#pragma unroll
            for (int nn = 0; nn < 2; ++nn) {
                const float bv = nn ? bv2_1 : bv2_0;
                const int f = nc + nn * 16 + l15;
#pragma unroll
                for (int i = 0; i < 4; ++i) {
                    const int r = m * 16 + kg * 4 + i;
                    const int t = t0 + r;
                    const int nv = 1 + (t < TLEN - DIL) + (t < TLEN - 2 * DIL);
                    float v = acc2[m][nn][i] + (float)nv * bv;
                    v = fmaxf(v, 0.0f);
                    v = fmaxf(v + rx[m][nn][i], 0.0f);
                    out[((size_t)b * TLEN + t) * CH + f] = v;
                }
            }
        }

        if (q < TPB - 1) __syncthreads();   // xs(q+1) visible; hs free
    }
}

// ---------------------------------------------------------------------------
extern "C" void kernel_launch(void* const* d_in, const int* in_sizes, int n_in,
                              void* d_out, int out_size, void* d_ws, size_t ws_size,
                              hipStream_t stream) {
    const float* x  = (const float*)d_in[0];
    const float* W1 = (const float*)d_in[1];
    const float* b1 = (const float*)d_in[2];
    const float* W2 = (const float*)d_in[3];
    const float* b2 = (const float*)d_in[4];
    float* out = (float*)d_out;

    _Float16* Wt1 = (_Float16*)d_ws;
    _Float16* Wt2 = Wt1 + KW * CH * CH;

    prep_weights_kernel<<<(2 * KW * CH * CH + 255) / 256, 256, 0, stream>>>(W1, W2, Wt1, Wt2);

    const int grid = BATCH * (TLEN / (BM * TPB));   // 512 persistent blocks
    fused_deconv_kernel<<<grid, 256, 0, stream>>>(x, Wt1, b1, Wt2, b2, out);
}